// Round 4
// baseline (204.804 us; speedup 1.0000x reference)
//
#include <hip/hip_runtime.h>
#include <hip/hip_fp16.h>

// ---------------------------------------------------------------------------
// SoftDecisionTreeEnsemble: N_TREES=15, DEPTH=3, INPUT_DIM=128, N_CLASSES=10
// R3: fix the defeated R2 pipeline. R2 kept both DMA buffers in ONE __shared__
// array indexed by i&1 -> waitcnt pass can't disambiguate -> conservative
// s_waitcnt vmcnt(0) before the first LDS op after DMA issue -> full HBM
// latency exposed per tile (R1 87.8us -> R2 82us, no change).
// Now: two distinct static __shared__ arrays + tile loop unrolled x2 with
// static buffer assignment. Alias-aware LDS-DMA waitcnt puts the wait only
// before the gather of the prefetched buffer. DMA is lane-linear (m97-style
// coalescing); banks fixed by +16B pad per 1024B chunk instead of swizzle.
// ---------------------------------------------------------------------------

typedef float    f32x4 __attribute__((ext_vector_type(4)));
typedef _Float16 half8 __attribute__((ext_vector_type(8)));

#define TREES      15
#define IDIM       128
#define NCLS       10
#define NINT       7
#define NLVS       8
#define PER_TREE   (NINT*IDIM + NINT + NLVS*NCLS)   // 983
#define NODES      (TREES*NINT)                     // 105
#define NPAD       112                              // 7 n-tiles of 16
#define KPAD       128                              // leaf K padded
#define RSTR       272                              // sigmoid/leaf row stride (bytes)
#define QSTR       1040                             // 1024B DMA chunk + 16B bank pad
#define QSZ        (8 * QSTR)                       // 8320 B per wave quarter
#define NBLK       512                              // 2 blocks/CU

// ---------------------------------------------------------------------------
// prep: wq[112][128] f16 (row g=7t+n, zero-padded), bq[112] f32 (zero-padded),
//       wbT[16][128] f16: wbT[c][8t+l] = softmax(leaf_logits[t][l])[c]*tw[t].
// Zero padding is load-bearing: pad nodes give z=0 -> sigmoid 0.5 (finite),
// which Phase A writes into cols 120..126; Phase B's masked tree-15 slot
// reads those (never garbage -> no NaN), and pad leaf cols multiply by 0.
// ---------------------------------------------------------------------------
__global__ __launch_bounds__(256) void prep_kernel(const float* __restrict__ p,
                                                   _Float16* __restrict__ wq,
                                                   float* __restrict__ bq,
                                                   _Float16* __restrict__ wbT) {
    const int gid  = blockIdx.x * 256 + threadIdx.x;
    const int nthr = gridDim.x * 256;

    for (int i = gid; i < NPAD * IDIM; i += nthr) {
        int g = i >> 7, k = i & 127;
        float v = 0.f;
        if (g < NODES) {
            int t = g / NINT, n = g % NINT;
            v = p[t * PER_TREE + n * IDIM + k];
        }
        wq[i] = (_Float16)v;
    }
    for (int i = gid; i < NPAD; i += nthr) {
        float v = 0.f;
        if (i < NODES) {
            int t = i / NINT, n = i % NINT;
            v = p[t * PER_TREE + NINT * IDIM + n];
        }
        bq[i] = v;
    }
    const float* tl = p + TREES * PER_TREE;
    for (int i = gid; i < 16 * KPAD; i += nthr) {
        int c = i >> 7, k = i & 127;
        float v = 0.f;
        if (c < NCLS && k < TREES * NLVS) {
            int t = k >> 3, l = k & 7;
            const float* ll = p + t * PER_TREE + NINT * IDIM + NINT + l * NCLS;
            float mx = ll[0];
            #pragma unroll
            for (int j = 1; j < NCLS; ++j) mx = fmaxf(mx, ll[j]);
            float se = 0.f;
            #pragma unroll
            for (int j = 0; j < NCLS; ++j) se += __expf(ll[j] - mx);
            float lsm = __expf(ll[c] - mx) / se;

            float m2 = tl[0];
            #pragma unroll
            for (int j = 1; j < TREES; ++j) m2 = fmaxf(m2, tl[j]);
            float s2 = 0.f;
            #pragma unroll
            for (int j = 0; j < TREES; ++j) s2 += __expf(tl[j] - m2);
            float tw = __expf(tl[t] - m2) / s2;
            v = lsm * tw;
        }
        wbT[i] = (_Float16)v;
    }
}

// Lane-linear DMA of one wave-quarter (16 rows x 512B): instruction `it`
// covers rows 2it (lanes 0-31) and 2it+1 (lanes 32-63), chunk = lane&31.
// LDS dest = qdst + it*QSTR + lane*16 (wave-uniform base, +16B pad per chunk).
__device__ __forceinline__ void dma_quarter(const float* __restrict__ x,
                                            long grow0, char* qdst, int lane) {
    #pragma unroll
    for (int it = 0; it < 8; ++it) {
        const float* gp = x + (grow0 + 2 * it + (lane >> 5)) * IDIM + (lane & 31) * 4;
        __builtin_amdgcn_global_load_lds(
            (const __attribute__((address_space(1))) void*)gp,
            (__attribute__((address_space(3))) void*)(qdst + it * QSTR),
            16, 0, 0);
    }
}

// ---------------------------------------------------------------------------
__global__ __launch_bounds__(256, 2) void tree_main(const float* __restrict__ x,
                                                    const _Float16* __restrict__ wq,
                                                    const float* __restrict__ bq,
                                                    const _Float16* __restrict__ wbT,
                                                    float* __restrict__ out,
                                                    int tpb) {
    // Two DISTINCT shared objects: the whole point of this round.
    __shared__ __align__(16) char ldsA[4 * QSZ];
    __shared__ __align__(16) char ldsB[4 * QSZ];

    const int tid  = threadIdx.x;
    const int lane = tid & 63;
    const int w    = tid >> 6;        // wave id: owns rows 16w..16w+15 of tile
    const int lm   = lane & 15;
    const int lq   = lane >> 4;
    const int rg   = lane >> 2;       // Phase B row (0..15)
    const int g    = lane & 3;        // Phase B tree group

    char* qA = &ldsA[w * QSZ];
    char* qB = &ldsB[w * QSZ];

    const long tile0 = (long)blockIdx.x * tpb;

    // prime the pipeline: tile 0 -> A
    dma_quarter(x, tile0 * 64 + 16 * w, qA, lane);

    // resident weights (compiler may remat from L1-resident wq; acceptable)
    half8 bf[7][4];
    float bb[7];
    #pragma unroll
    for (int nt = 0; nt < 7; ++nt) {
        bb[nt] = bq[16 * nt + lm];
        #pragma unroll
        for (int s = 0; s < 4; ++s)
            bf[nt][s] = *reinterpret_cast<const half8*>(wq + (16 * nt + lm) * IDIM + 32 * s + 8 * lq);
    }
    half8 wbf[4];
    #pragma unroll
    for (int s = 0; s < 4; ++s)
        wbf[s] = *reinterpret_cast<const half8*>(wbT + lm * KPAD + 32 * s + 8 * lq);

    // A-fragment gather from padded lane-linear layout + cvt f32->f16.
    // Row r base = (r>>1)*QSTR + (r&1)*512; k-chunk byte = (32s+8lq)*4.
    auto gather = [&](const char* q, half8 af[4]) {
        #pragma unroll
        for (int s = 0; s < 4; ++s) {
            const char* p0 = q + (lm >> 1) * QSTR + (lm & 1) * 512 + 128 * s + 32 * lq;
            f32x4 f0 = *(const f32x4*)(p0);
            f32x4 f1 = *(const f32x4*)(p0 + 16);
            half8 a;
            #pragma unroll
            for (int j = 0; j < 4; ++j) {
                a[j]     = (_Float16)f0[j];
                a[j + 4] = (_Float16)f1[j];
            }
            af[s] = a;
        }
    };

    auto compute = [&](char* q, const half8 af[4], long grow) {
        // ---- Phase A: z-GEMM + sigmoid -> packed cols 8t+n ----
        #pragma unroll
        for (int nt = 0; nt < 7; ++nt) {
            f32x4 acc = {0.f, 0.f, 0.f, 0.f};
            #pragma unroll
            for (int s = 0; s < 4; ++s)
                acc = __builtin_amdgcn_mfma_f32_16x16x32_f16(af[s], bf[nt][s], acc, 0, 0, 0);
            int node = 16 * nt + lm;
            int col  = node + ((node * 9363) >> 16);   // node + node/7 = 8t+n
            #pragma unroll
            for (int r = 0; r < 4; ++r) {
                float z  = acc[r] + bb[nt];            // C/D: row=4lq+r, col=lm
                float sg = __builtin_amdgcn_rcpf(1.0f + __expf(-z));
                *(_Float16*)(q + (4 * lq + r) * RSTR + col * 2) = (_Float16)sg;
            }
        }

        // ---- Phase B: leaf probabilities (wave-lockstep, reads before writes) ----
        {
            const char* rowp = q + rg * RSTR;
            float sgv[4][7];
            #pragma unroll
            for (int tt = 0; tt < 4; ++tt) {
                #pragma unroll
                for (int n = 0; n < 7; ++n)
                    sgv[tt][n] = (float)*(const _Float16*)(rowp + (8 * (4 * g + tt) + n) * 2);
            }
            half8 lv[4];
            #pragma unroll
            for (int tt = 0; tt < 4; ++tt) {
                float s0 = sgv[tt][0], s1 = sgv[tt][1], s2 = sgv[tt][2];
                float s3 = sgv[tt][3], s4 = sgv[tt][4], s5 = sgv[tt][5], s6 = sgv[tt][6];
                float u1 = 1.f - s0, u2 = s0;
                float q1 = u1 * s1, q0 = u1 - q1;
                float q3 = u2 * s2, q2 = u2 - q3;
                float L1 = q0 * s3, L0 = q0 - L1;
                float L3 = q1 * s4, L2 = q1 - L3;
                float L5 = q2 * s5, L4 = q2 - L5;
                float L7 = q3 * s6, L6 = q3 - L7;
                float m = (4 * g + tt < TREES) ? 1.f : 0.f;   // zero tree-15 slot
                half8 lv8;
                lv8[0] = (_Float16)(L0 * m); lv8[1] = (_Float16)(L1 * m);
                lv8[2] = (_Float16)(L2 * m); lv8[3] = (_Float16)(L3 * m);
                lv8[4] = (_Float16)(L4 * m); lv8[5] = (_Float16)(L5 * m);
                lv8[6] = (_Float16)(L6 * m); lv8[7] = (_Float16)(L7 * m);
                lv[tt] = lv8;
            }
            #pragma unroll
            for (int tt = 0; tt < 4; ++tt)
                *(half8*)(q + rg * RSTR + 64 * g + 16 * tt) = lv[tt];
        }

        // ---- Phase C: leaf x wbT MFMA -> out ----
        {
            half8 af2[4];
            #pragma unroll
            for (int s = 0; s < 4; ++s)
                af2[s] = *(const half8*)(q + lm * RSTR + 64 * s + 16 * lq);
            f32x4 a2 = {0.f, 0.f, 0.f, 0.f};
            #pragma unroll
            for (int s = 0; s < 4; ++s)
                a2 = __builtin_amdgcn_mfma_f32_16x16x32_f16(af2[s], wbf[s], a2, 0, 0, 0);
            if (lm < NCLS) {
                #pragma unroll
                for (int r = 0; r < 4; ++r)
                    out[(grow + 16 * w + 4 * lq + r) * NCLS + lm] = a2[r];
            }
        }
    };

    // tile loop, unrolled x2 with STATIC buffer assignment (tpb is even)
    for (int i = 0; i < tpb; i += 2) {
        half8 af[4];
        // body A: compute tile i from qA, prefetch tile i+1 -> qB
        gather(qA, af);                                        // waits own DMA->A
        dma_quarter(x, (tile0 + i + 1) * 64 + 16 * w, qB, lane);
        compute(qA, af, (tile0 + i) * 64);                     // no wait on B-DMA

        // body B: compute tile i+1 from qB, prefetch tile i+2 -> qA
        gather(qB, af);                                        // waits DMA->B
        if (i + 2 < tpb)
            dma_quarter(x, (tile0 + i + 2) * 64 + 16 * w, qA, lane);
        compute(qB, af, (tile0 + i + 1) * 64);
    }
}

// ---------------------------------------------------------------------------
extern "C" void kernel_launch(void* const* d_in, const int* in_sizes, int n_in,
                              void* d_out, int out_size, void* d_ws, size_t ws_size,
                              hipStream_t stream) {
    const float* x      = (const float*)d_in[0];
    const float* params = (const float*)d_in[1];
    float* out = (float*)d_out;

    _Float16* wq  = (_Float16*)d_ws;                             // 28672 B
    float*    bq  = (float*)((char*)d_ws + NPAD * IDIM * 2);     // 448 B
    _Float16* wbT = (_Float16*)((char*)bq + NPAD * 4);           // 4096 B

    const int batch = in_sizes[0] / IDIM;      // 262144
    const int tiles = batch / 64;              // 4096
    const int tpb   = tiles / NBLK;            // 8 (even; loop relies on it)

    prep_kernel<<<8, 256, 0, stream>>>(params, wq, bq, wbT);
    tree_main<<<NBLK, 256, 0, stream>>>(x, wq, bq, wbT, out, tpb);
}